// Round 1
// baseline (204.777 us; speedup 1.0000x reference)
//
#include <hip/hip_runtime.h>
#include <math.h>

#define NB   16
#define CIN  64
#define LEN  8192
#define COUT 64
#define MSZ  192   // C_IN * K
#define HM   96    // half of MSZ
#define BST  68    // LDS row stride (floats): 64 + 4 pad, keeps 16B alignment

// ---------------- Kernel A: offset conv -> grid positions ----------------
// grid[n,l,k] = clip((l+1) + conv(x, w_off)[n, 2k, l], 0, 8193)
__global__ __launch_bounds__(256) void offs_kernel(
    const float* __restrict__ x, const float* __restrict__ w_off,
    const float* __restrict__ b_off, float* __restrict__ gbuf)
{
    __shared__ float wk[3 * 192];   // wk[k*192 + ci*3 + t] = w_off[2k][ci][t]
    int tid = threadIdx.x;
    for (int i = tid; i < 576; i += 256) {
        int k   = i / 192;
        int rem = i - k * 192;
        wk[i] = w_off[2 * k * 192 + rem];
    }
    __syncthreads();

    int n = blockIdx.x >> 5;                 // 32 blocks of 256 per batch
    int l = ((blockIdx.x & 31) << 8) | tid;  // 0..8191
    const float* xn = x + (size_t)n * (CIN * LEN);

    float a0 = b_off[0], a1 = b_off[2], a2 = b_off[4];
    #pragma unroll 4
    for (int ci = 0; ci < CIN; ++ci) {
        const float* xc = xn + ci * LEN;
        float xm = (l >= 1)       ? xc[l - 1] : 0.f;
        float x0 = xc[l];
        float xp = (l < LEN - 1)  ? xc[l + 1] : 0.f;
        const float* w0 = &wk[ci * 3];
        const float* w1 = &wk[192 + ci * 3];
        const float* w2 = &wk[384 + ci * 3];
        a0 = fmaf(w0[0], xm, a0); a0 = fmaf(w0[1], x0, a0); a0 = fmaf(w0[2], xp, a0);
        a1 = fmaf(w1[0], xm, a1); a1 = fmaf(w1[1], x0, a1); a1 = fmaf(w1[2], xp, a1);
        a2 = fmaf(w2[0], xm, a2); a2 = fmaf(w2[1], x0, a2); a2 = fmaf(w2[2], xp, a2);
    }
    float base = (float)(l + 1);
    float g0 = fminf(fmaxf(base + a0, 0.f), 8193.f);
    float g1 = fminf(fmaxf(base + a1, 0.f), 8193.f);
    float g2 = fminf(fmaxf(base + a2, 0.f), 8193.f);
    size_t gi = ((size_t)n * LEN + l) * 3;
    gbuf[gi + 0] = g0; gbuf[gi + 1] = g1; gbuf[gi + 2] = g2;
}

// ---------------- Kernel B: gather + lerp + 64x64x192 GEMM per (n,p) ----------------
__global__ __launch_bounds__(256) void dconv_kernel(
    const float* __restrict__ x, const float* __restrict__ w,
    const float* __restrict__ bias, const float* __restrict__ gbuf,
    float* __restrict__ out)
{
    __shared__ __align__(16) float Wl[HM * BST];    // Wl[ml][o]
    __shared__ __align__(16) float Blds[HM * BST];  // Blds[ml][cc]
    __shared__ int   lidx[MSZ];
    __shared__ float alph[MSZ];

    int tid = threadIdx.x;
    int n = blockIdx.x >> 7;
    int p = blockIdx.x & 127;
    const float* xn = x + (size_t)n * (CIN * LEN);

    // grid -> left index (padded coords) + alpha, for all 192 m
    if (tid < MSZ) {
        int k = tid >> 6;
        int r = tid & 63;
        int l = (r << 7) | p;
        float g  = gbuf[((size_t)n * LEN + l) * 3 + k];
        float fl = floorf(g);
        lidx[tid] = (int)fl;
        alph[tid] = g - fl;
    }
    // stage W half 0 (transposed): Wl[ml][o] = w[o*192 + ml]
    for (int j = tid; j < HM * COUT; j += 256) {
        int o  = j / HM;
        int ml = j - o * HM;
        Wl[ml * BST + o] = w[o * MSZ + ml];
    }
    __syncthreads();

    // build B half 0: Blds[ml][cc] = lerp gather
    for (int j = tid; j < HM * CIN; j += 256) {
        int cc = j & 63;
        int ml = j >> 6;
        int lv = lidx[ml];
        float a = alph[ml];
        const float* xc = xn + cc * LEN;
        float xl = (lv >= 1 && lv <= LEN) ? xc[lv - 1] : 0.f;
        int rv = lv + 1; if (rv > LEN + 1) rv = LEN + 1;
        float xr = (rv >= 1 && rv <= LEN) ? xc[rv - 1] : 0.f;
        Blds[ml * BST + cc] = fmaf(a, xr - xl, xl);
    }
    __syncthreads();

    int tx = tid & 15, ty = tid >> 4;
    int o0 = ty << 2, c0 = tx << 2;
    float acc[4][4] = {{0.f,0.f,0.f,0.f},{0.f,0.f,0.f,0.f},{0.f,0.f,0.f,0.f},{0.f,0.f,0.f,0.f}};

    // GEMM half 0
    #pragma unroll 8
    for (int ml = 0; ml < HM; ++ml) {
        float4 wv = *(const float4*)&Wl[ml * BST + o0];
        float4 bv = *(const float4*)&Blds[ml * BST + c0];
        acc[0][0] = fmaf(wv.x, bv.x, acc[0][0]); acc[0][1] = fmaf(wv.x, bv.y, acc[0][1]);
        acc[0][2] = fmaf(wv.x, bv.z, acc[0][2]); acc[0][3] = fmaf(wv.x, bv.w, acc[0][3]);
        acc[1][0] = fmaf(wv.y, bv.x, acc[1][0]); acc[1][1] = fmaf(wv.y, bv.y, acc[1][1]);
        acc[1][2] = fmaf(wv.y, bv.z, acc[1][2]); acc[1][3] = fmaf(wv.y, bv.w, acc[1][3]);
        acc[2][0] = fmaf(wv.z, bv.x, acc[2][0]); acc[2][1] = fmaf(wv.z, bv.y, acc[2][1]);
        acc[2][2] = fmaf(wv.z, bv.z, acc[2][2]); acc[2][3] = fmaf(wv.z, bv.w, acc[2][3]);
        acc[3][0] = fmaf(wv.w, bv.x, acc[3][0]); acc[3][1] = fmaf(wv.w, bv.y, acc[3][1]);
        acc[3][2] = fmaf(wv.w, bv.z, acc[3][2]); acc[3][3] = fmaf(wv.w, bv.w, acc[3][3]);
    }
    __syncthreads();

    // stage half 1
    for (int j = tid; j < HM * COUT; j += 256) {
        int o  = j / HM;
        int ml = j - o * HM;
        Wl[ml * BST + o] = w[o * MSZ + HM + ml];
    }
    for (int j = tid; j < HM * CIN; j += 256) {
        int cc = j & 63;
        int ml = j >> 6;
        int m  = HM + ml;
        int lv = lidx[m];
        float a = alph[m];
        const float* xc = xn + cc * LEN;
        float xl = (lv >= 1 && lv <= LEN) ? xc[lv - 1] : 0.f;
        int rv = lv + 1; if (rv > LEN + 1) rv = LEN + 1;
        float xr = (rv >= 1 && rv <= LEN) ? xc[rv - 1] : 0.f;
        Blds[ml * BST + cc] = fmaf(a, xr - xl, xl);
    }
    __syncthreads();

    // GEMM half 1
    #pragma unroll 8
    for (int ml = 0; ml < HM; ++ml) {
        float4 wv = *(const float4*)&Wl[ml * BST + o0];
        float4 bv = *(const float4*)&Blds[ml * BST + c0];
        acc[0][0] = fmaf(wv.x, bv.x, acc[0][0]); acc[0][1] = fmaf(wv.x, bv.y, acc[0][1]);
        acc[0][2] = fmaf(wv.x, bv.z, acc[0][2]); acc[0][3] = fmaf(wv.x, bv.w, acc[0][3]);
        acc[1][0] = fmaf(wv.y, bv.x, acc[1][0]); acc[1][1] = fmaf(wv.y, bv.y, acc[1][1]);
        acc[1][2] = fmaf(wv.y, bv.z, acc[1][2]); acc[1][3] = fmaf(wv.y, bv.w, acc[1][3]);
        acc[2][0] = fmaf(wv.z, bv.x, acc[2][0]); acc[2][1] = fmaf(wv.z, bv.y, acc[2][1]);
        acc[2][2] = fmaf(wv.z, bv.z, acc[2][2]); acc[2][3] = fmaf(wv.z, bv.w, acc[2][3]);
        acc[3][0] = fmaf(wv.w, bv.x, acc[3][0]); acc[3][1] = fmaf(wv.w, bv.y, acc[3][1]);
        acc[3][2] = fmaf(wv.w, bv.z, acc[3][2]); acc[3][3] = fmaf(wv.w, bv.w, acc[3][3]);
    }

    // write out: out[n][o][p*64 + cc]
    int q0 = (p << 6) | c0;
    #pragma unroll
    for (int i = 0; i < 4; ++i) {
        int o = o0 + i;
        float bb = bias[o];
        float4 r4;
        r4.x = acc[i][0] + bb;
        r4.y = acc[i][1] + bb;
        r4.z = acc[i][2] + bb;
        r4.w = acc[i][3] + bb;
        *(float4*)&out[((size_t)n * COUT + o) * LEN + q0] = r4;
    }
}

extern "C" void kernel_launch(void* const* d_in, const int* in_sizes, int n_in,
                              void* d_out, int out_size, void* d_ws, size_t ws_size,
                              hipStream_t stream) {
    const float* x     = (const float*)d_in[0];
    const float* w_off = (const float*)d_in[1];
    const float* b_off = (const float*)d_in[2];
    const float* w     = (const float*)d_in[3];
    const float* b     = (const float*)d_in[4];
    float* out  = (float*)d_out;
    float* gbuf = (float*)d_ws;   // needs 16*8192*3*4 = 1.57 MB

    offs_kernel<<<NB * (LEN / 256), 256, 0, stream>>>(x, w_off, b_off, gbuf);
    dconv_kernel<<<NB * 128, 256, 0, stream>>>(x, w, b, gbuf, out);
}

// Round 2
// 87.504 us; speedup vs baseline: 2.3402x; 2.3402x over previous
//
#include <hip/hip_runtime.h>
#include <math.h>

#define NB   16
#define CIN  64
#define LEN  8192
#define LP   8194      // padded length (rows 0 and 8193 are zero)
#define COUT 64
#define MSZ  192       // C_IN * K
#define KC   48        // K-chunk
#define NKC  4
#define BST  68        // LDS row stride (floats)

// ---------------- Kernel A: offset conv -> grid positions ----------------
// gbuf[n][l][k] = clip((l+1) + conv(x, w_off)[n, 2k, l], 0, 8193)
__global__ __launch_bounds__(256) void offs_kernel(
    const float* __restrict__ x, const float* __restrict__ w_off,
    const float* __restrict__ b_off, float* __restrict__ gbuf)
{
    __shared__ float wk[3 * 192];   // wk[k*192 + ci*3 + t] = w_off[2k][ci][t]
    int tid = threadIdx.x;
    for (int i = tid; i < 576; i += 256) {
        int k   = i / 192;
        int rem = i - k * 192;
        wk[i] = w_off[2 * k * 192 + rem];
    }
    __syncthreads();

    int n = blockIdx.x >> 5;
    int l = ((blockIdx.x & 31) << 8) | tid;
    const float* xn = x + (size_t)n * (CIN * LEN);

    float a0 = b_off[0], a1 = b_off[2], a2 = b_off[4];
    #pragma unroll 4
    for (int ci = 0; ci < CIN; ++ci) {
        const float* xc = xn + ci * LEN;
        float xm = (l >= 1)       ? xc[l - 1] : 0.f;
        float x0 = xc[l];
        float xp = (l < LEN - 1)  ? xc[l + 1] : 0.f;
        const float* w0 = &wk[ci * 3];
        const float* w1 = &wk[192 + ci * 3];
        const float* w2 = &wk[384 + ci * 3];
        a0 = fmaf(w0[0], xm, a0); a0 = fmaf(w0[1], x0, a0); a0 = fmaf(w0[2], xp, a0);
        a1 = fmaf(w1[0], xm, a1); a1 = fmaf(w1[1], x0, a1); a1 = fmaf(w1[2], xp, a1);
        a2 = fmaf(w2[0], xm, a2); a2 = fmaf(w2[1], x0, a2); a2 = fmaf(w2[2], xp, a2);
    }
    float base = (float)(l + 1);
    float g0 = fminf(fmaxf(base + a0, 0.f), 8193.f);
    float g1 = fminf(fmaxf(base + a1, 0.f), 8193.f);
    float g2 = fminf(fmaxf(base + a2, 0.f), 8193.f);
    size_t gi = ((size_t)n * LEN + l) * 3;
    gbuf[gi + 0] = g0; gbuf[gi + 1] = g1; gbuf[gi + 2] = g2;
}

// ---------------- Kernel W: transpose w -> wt[m][o] ----------------
__global__ __launch_bounds__(256) void wtrans_kernel(
    const float* __restrict__ w, float* __restrict__ wt)
{
    int j = blockIdx.x * 256 + threadIdx.x;   // 12288 elements
    if (j < MSZ * COUT) {
        int ml = j >> 6, o = j & 63;
        wt[j] = w[o * MSZ + ml];
    }
}

// ---------------- Kernel X: transpose x -> xt[n][lp][c] (padded) ----------------
__global__ __launch_bounds__(256) void xtrans_kernel(
    const float* __restrict__ x, float* __restrict__ xt)
{
    __shared__ float tile[64 * 65];
    int tid = threadIdx.x;
    int n = blockIdx.x >> 7;
    int t = blockIdx.x & 127;
    int l0 = t << 6;

    // read: 64 c-rows x 64 l, coalesced along l
    for (int j = tid; j < 4096; j += 256) {
        int cl = j >> 6, ll = j & 63;
        tile[cl * 65 + ll] = x[((size_t)n * CIN + cl) * LEN + l0 + ll];
    }
    __syncthreads();
    // write: 64 l-rows x 64 c, coalesced along c; LDS read stride 65 -> conflict-free
    for (int j = tid; j < 4096; j += 256) {
        int ll = j >> 6, cl = j & 63;
        xt[((size_t)n * LP + 1 + l0 + ll) * 64 + cl] = tile[cl * 65 + ll];
    }
    // zero pad rows
    if (t == 0 && tid < 64)
        xt[((size_t)n * LP + 0) * 64 + tid] = 0.f;
    if (t == 127 && tid < 64)
        xt[((size_t)n * LP + LEN + 1) * 64 + tid] = 0.f;
}

// ---------------- Kernel B: gather + lerp + 64x64x192 GEMM per (n,p) ----------------
template<bool USE_XT>
__global__ __launch_bounds__(256) void dconv2_kernel(
    const float* __restrict__ x, const float* __restrict__ xt,
    const float* __restrict__ wt, const float* __restrict__ bias,
    const float* __restrict__ gbuf, float* __restrict__ out)
{
    __shared__ __align__(16) float Wl[KC * BST];   // Wl[mlc][o]
    __shared__ __align__(16) float Bl[KC * BST];   // Bl[mlc][cc]
    __shared__ int   lidx[MSZ];
    __shared__ float alph[MSZ];

    int tid = threadIdx.x;
    int n = blockIdx.x >> 7;
    int p = blockIdx.x & 127;

    if (tid < MSZ) {
        int k = tid >> 6, r = tid & 63;
        int l = (r << 7) | p;
        float g  = gbuf[((size_t)n * LEN + l) * 3 + k];
        float fl = floorf(g);
        lidx[tid] = (int)fl;
        alph[tid] = g - fl;
    }
    __syncthreads();

    int tx = tid & 15, ty = tid >> 4;
    int o0 = ty << 2, c0 = tx << 2;
    float acc[4][4] = {{0.f,0.f,0.f,0.f},{0.f,0.f,0.f,0.f},{0.f,0.f,0.f,0.f},{0.f,0.f,0.f,0.f}};

    const float* xtn = xt + (size_t)n * ((size_t)LP * 64);
    const float* xn  = x  + (size_t)n * (CIN * LEN);

    for (int kc = 0; kc < NKC; ++kc) {
        // stage W chunk: coalesced float4 read, conflict-free LDS write
        for (int j = tid; j < KC * 16; j += 256) {
            int mlc = j >> 4, o4 = (j & 15) << 2;
            float4 wv = *(const float4*)&wt[(size_t)(kc * KC + mlc) * 64 + o4];
            *(float4*)&Wl[mlc * BST + o4] = wv;
        }
        // build B chunk
        if (USE_XT) {
            for (int j = tid; j < KC * 16; j += 256) {
                int mlc = j >> 4, c4 = (j & 15) << 2;
                int m  = kc * KC + mlc;
                int lv = lidx[m];
                float a = alph[m];
                int rv = lv + 1; if (rv > LEN + 1) rv = LEN + 1;
                float4 xl = *(const float4*)&xtn[(size_t)lv * 64 + c4];
                float4 xr = *(const float4*)&xtn[(size_t)rv * 64 + c4];
                float4 bv;
                bv.x = fmaf(a, xr.x - xl.x, xl.x);
                bv.y = fmaf(a, xr.y - xl.y, xl.y);
                bv.z = fmaf(a, xr.z - xl.z, xl.z);
                bv.w = fmaf(a, xr.w - xl.w, xl.w);
                *(float4*)&Bl[mlc * BST + c4] = bv;
            }
        } else {
            for (int j = tid; j < KC * 64; j += 256) {
                int mlc = j >> 6, cc = j & 63;
                int m  = kc * KC + mlc;
                int lv = lidx[m];
                float a = alph[m];
                const float* xc = xn + cc * LEN;
                float xl = (lv >= 1 && lv <= LEN) ? xc[lv - 1] : 0.f;
                int rv = lv + 1; if (rv > LEN + 1) rv = LEN + 1;
                float xr = (rv >= 1 && rv <= LEN) ? xc[rv - 1] : 0.f;
                Bl[mlc * BST + cc] = fmaf(a, xr - xl, xl);
            }
        }
        __syncthreads();

        #pragma unroll 8
        for (int ml = 0; ml < KC; ++ml) {
            float4 wv = *(const float4*)&Wl[ml * BST + o0];
            float4 bv = *(const float4*)&Bl[ml * BST + c0];
            acc[0][0] = fmaf(wv.x, bv.x, acc[0][0]); acc[0][1] = fmaf(wv.x, bv.y, acc[0][1]);
            acc[0][2] = fmaf(wv.x, bv.z, acc[0][2]); acc[0][3] = fmaf(wv.x, bv.w, acc[0][3]);
            acc[1][0] = fmaf(wv.y, bv.x, acc[1][0]); acc[1][1] = fmaf(wv.y, bv.y, acc[1][1]);
            acc[1][2] = fmaf(wv.y, bv.z, acc[1][2]); acc[1][3] = fmaf(wv.y, bv.w, acc[1][3]);
            acc[2][0] = fmaf(wv.z, bv.x, acc[2][0]); acc[2][1] = fmaf(wv.z, bv.y, acc[2][1]);
            acc[2][2] = fmaf(wv.z, bv.z, acc[2][2]); acc[2][3] = fmaf(wv.z, bv.w, acc[2][3]);
            acc[3][0] = fmaf(wv.w, bv.x, acc[3][0]); acc[3][1] = fmaf(wv.w, bv.y, acc[3][1]);
            acc[3][2] = fmaf(wv.w, bv.z, acc[3][2]); acc[3][3] = fmaf(wv.w, bv.w, acc[3][3]);
        }
        __syncthreads();
    }

    // write out: out[n][o][p*64 + cc]
    int q0 = (p << 6) | c0;
    #pragma unroll
    for (int i = 0; i < 4; ++i) {
        int o = o0 + i;
        float bb = bias[o];
        float4 r4;
        r4.x = acc[i][0] + bb;
        r4.y = acc[i][1] + bb;
        r4.z = acc[i][2] + bb;
        r4.w = acc[i][3] + bb;
        *(float4*)&out[((size_t)n * COUT + o) * LEN + q0] = r4;
    }
}

extern "C" void kernel_launch(void* const* d_in, const int* in_sizes, int n_in,
                              void* d_out, int out_size, void* d_ws, size_t ws_size,
                              hipStream_t stream) {
    const float* x     = (const float*)d_in[0];
    const float* w_off = (const float*)d_in[1];
    const float* b_off = (const float*)d_in[2];
    const float* w     = (const float*)d_in[3];
    const float* b     = (const float*)d_in[4];
    float* out = (float*)d_out;

    // workspace layout
    const size_t GBUF_B = (size_t)NB * LEN * 3 * 4;            // 6,291,456
    const size_t WT_B   = (size_t)MSZ * COUT * 4;              // 49,152
    const size_t XT_B   = (size_t)NB * LP * 64 * 4;            // 33,562,624
    float* gbuf = (float*)d_ws;
    float* wt   = (float*)((char*)d_ws + GBUF_B);
    float* xt   = (float*)((char*)d_ws + GBUF_B + WT_B);
    bool big_ws = (ws_size >= GBUF_B + WT_B + XT_B);

    offs_kernel<<<NB * (LEN / 256), 256, 0, stream>>>(x, w_off, b_off, gbuf);
    if (big_ws) {
        wtrans_kernel<<<(MSZ * COUT + 255) / 256, 256, 0, stream>>>(w, wt);
        xtrans_kernel<<<NB * (LEN / 64), 256, 0, stream>>>(x, xt);
        dconv2_kernel<true><<<NB * 128, 256, 0, stream>>>(x, xt, wt, b, gbuf, out);
    } else if (ws_size >= GBUF_B + WT_B) {
        wtrans_kernel<<<(MSZ * COUT + 255) / 256, 256, 0, stream>>>(w, wt);
        dconv2_kernel<false><<<NB * 128, 256, 0, stream>>>(x, xt, wt, b, gbuf, out);
    }
}

// Round 3
// 59.682 us; speedup vs baseline: 3.4311x; 1.4662x over previous
//
#include <hip/hip_runtime.h>
#include <hip/hip_bf16.h>
#include <math.h>

#define NB   16
#define CIN  64
#define LEN  8192
#define LP2  8195     // rows: 0 = left pad(0), 1..8192 = x, 8193 = right pad(0), 8194 = safety(0)
#define COUT 64
#define MSZ  192

typedef float  f32x4  __attribute__((ext_vector_type(4)));
typedef short  bf16x8 __attribute__((ext_vector_type(8)));

static __device__ inline unsigned short f2bf(float f) {
    __hip_bfloat16 h = __float2bfloat16(f);
    return *reinterpret_cast<unsigned short*>(&h);
}

// ---------------- Kernel F: fused offset-conv + transpose-to-bf16 ----------------
__global__ __launch_bounds__(256) void fused_off_trans(
    const float* __restrict__ x, const float* __restrict__ w_off,
    const float* __restrict__ b_off, float* __restrict__ gbuf,
    unsigned int* __restrict__ xt32)
{
    __shared__ float tile[64][131];   // [c][l0-1 .. l0+128], padded stride
    __shared__ float wk[576];         // wk[k*192 + ci*3 + t] = w_off[2k][ci][t]
    int tid = threadIdx.x;
    int n = blockIdx.x >> 6;
    int t = blockIdx.x & 63;
    int l0 = t << 7;

    for (int i = tid; i < 576; i += 256) {
        int k = i / 192, rem = i - k * 192;
        wk[i] = w_off[2 * k * 192 + rem];
    }
    for (int j = tid; j < 64 * 130; j += 256) {
        int cc = j / 130, ll = j - cc * 130;
        int gl = l0 - 1 + ll;
        float v = (gl >= 0 && gl < LEN) ? x[((size_t)n * CIN + cc) * LEN + gl] : 0.f;
        tile[cc][ll] = v;
    }
    __syncthreads();

    // offset conv: thread pair (l_loc, h) — each half does 32 channels
    {
        int l_loc = tid >> 1, h = tid & 1;
        int c0 = h << 5;
        float a0 = 0.f, a1 = 0.f, a2 = 0.f;
        #pragma unroll
        for (int ci = 0; ci < 32; ++ci) {
            int cc = c0 + ci;
            float xm = tile[cc][l_loc];
            float x0 = tile[cc][l_loc + 1];
            float xp = tile[cc][l_loc + 2];
            const float* w0 = &wk[cc * 3];
            const float* w1 = &wk[192 + cc * 3];
            const float* w2 = &wk[384 + cc * 3];
            a0 = fmaf(w0[0], xm, a0); a0 = fmaf(w0[1], x0, a0); a0 = fmaf(w0[2], xp, a0);
            a1 = fmaf(w1[0], xm, a1); a1 = fmaf(w1[1], x0, a1); a1 = fmaf(w1[2], xp, a1);
            a2 = fmaf(w2[0], xm, a2); a2 = fmaf(w2[1], x0, a2); a2 = fmaf(w2[2], xp, a2);
        }
        a0 += __shfl_xor(a0, 1);
        a1 += __shfl_xor(a1, 1);
        a2 += __shfl_xor(a2, 1);
        if (h == 0) {
            int l = l0 + l_loc;
            float base = (float)(l + 1);
            float g0 = fminf(fmaxf(base + a0 + b_off[0], 0.f), 8193.f);
            float g1 = fminf(fmaxf(base + a1 + b_off[2], 0.f), 8193.f);
            float g2 = fminf(fmaxf(base + a2 + b_off[4], 0.f), 8193.f);
            size_t gi = ((size_t)n * LEN + l) * 3;
            gbuf[gi + 0] = g0; gbuf[gi + 1] = g1; gbuf[gi + 2] = g2;
        }
    }

    // transpose to bf16: xt[row = 1+l][c], packed 2 bf16 per u32
    for (int j = tid; j < 128 * 32; j += 256) {
        int ll = j >> 5, cp = j & 31;
        int c = cp << 1;
        unsigned int u = ((unsigned int)f2bf(tile[c + 1][ll + 1]) << 16) | f2bf(tile[c][ll + 1]);
        xt32[((size_t)n * LP2 + 1 + l0 + ll) * 32 + cp] = u;
    }
    if (t == 0  && tid < 32) xt32[((size_t)n * LP2) * 32 + tid] = 0u;
    if (t == 63 && tid < 64) xt32[((size_t)n * LP2 + 8193 + (tid >> 5)) * 32 + (tid & 31)] = 0u;
}

// ---------------- Kernel W: pack w into MFMA B-fragment order (bf16) ----------------
// wtf[((ot*6 + ks)*64 + lane)*8 + s] = bf16( w[ ot*16+(lane&15) ][ ks*32 + (lane>>4)*8 + s ] )
__global__ __launch_bounds__(512) void wfrag_kernel(
    const float* __restrict__ w, unsigned short* __restrict__ wtf)
{
    int b = blockIdx.x;             // 24 blocks: b = ot*6 + ks
    int ot = b / 6, ks = b - ot * 6;
    int t = threadIdx.x;            // 512
    int l = t >> 3, s = t & 7;
    int o = ot * 16 + (l & 15);
    int m = ks * 32 + (l >> 4) * 8 + s;
    wtf[b * 512 + t] = f2bf(w[o * MSZ + m]);
}

// ---------------- Kernel D: register-gather + bf16 MFMA ----------------
__global__ __launch_bounds__(256) void dconv3_kernel(
    const unsigned short* __restrict__ xt16, const unsigned short* __restrict__ wtf,
    const float* __restrict__ bias, const float* __restrict__ gbuf,
    float* __restrict__ out)
{
    __shared__ __align__(16) int2 meta[MSZ];   // (left index, alpha bits)
    int tid = threadIdx.x;
    int n = blockIdx.x >> 7;
    int p = blockIdx.x & 127;

    if (tid < MSZ) {
        int k = tid >> 6, r = tid & 63;
        int l = (r << 7) | p;
        float g  = gbuf[((size_t)n * LEN + l) * 3 + k];
        float fl = floorf(g);
        meta[tid] = make_int2((int)fl, __float_as_int(g - fl));
    }
    __syncthreads();

    int lane = tid & 63;
    int ct   = tid >> 6;            // wave id = c-tile (16 channels)
    int g4   = lane >> 4;
    int c    = ct * 16 + (lane & 15);
    const unsigned short* xb = xt16 + (size_t)n * LP2 * 64;  // uniform base (saddr form)

    f32x4 acc[4] = {};   // one per o-tile

    #pragma unroll
    for (int ks = 0; ks < 6; ++ks) {
        int mb = ks * 32 + g4 * 8;
        int2 mm[8];
        #pragma unroll
        for (int q = 0; q < 4; ++q)
            *(int4*)&mm[q * 2] = *(const int4*)&meta[mb + q * 2];

        bf16x8 afrag;
        #pragma unroll
        for (int s = 0; s < 8; ++s) {
            int   lv = mm[s].x;
            float a  = __int_as_float(mm[s].y);
            unsigned int off = ((unsigned int)lv << 6) + (unsigned int)c;
            float xl = __uint_as_float((unsigned int)xb[off]      << 16);
            float xr = __uint_as_float((unsigned int)xb[off + 64] << 16);
            afrag[s] = (short)f2bf(fmaf(a, xr - xl, xl));
        }

        #pragma unroll
        for (int ot = 0; ot < 4; ++ot) {
            bf16x8 bfrag = *(const bf16x8*)&wtf[(size_t)(((ot * 6 + ks) << 6) + lane) << 3];
            acc[ot] = __builtin_amdgcn_mfma_f32_16x16x32_bf16(afrag, bfrag, acc[ot], 0, 0, 0);
        }
    }

    // D layout: col(o) = lane&15, row(c) = (lane>>4)*4 + reg  -> float4 along output q
    int q0 = (p << 6) + ct * 16 + g4 * 4;
    #pragma unroll
    for (int ot = 0; ot < 4; ++ot) {
        int o = ot * 16 + (lane & 15);
        float bb = bias[o];
        float4 r4;
        r4.x = acc[ot][0] + bb;
        r4.y = acc[ot][1] + bb;
        r4.z = acc[ot][2] + bb;
        r4.w = acc[ot][3] + bb;
        *(float4*)&out[((size_t)n * COUT + o) * LEN + q0] = r4;
    }
}

extern "C" void kernel_launch(void* const* d_in, const int* in_sizes, int n_in,
                              void* d_out, int out_size, void* d_ws, size_t ws_size,
                              hipStream_t stream) {
    const float* x     = (const float*)d_in[0];
    const float* w_off = (const float*)d_in[1];
    const float* b_off = (const float*)d_in[2];
    const float* w     = (const float*)d_in[3];
    const float* b     = (const float*)d_in[4];
    float* out = (float*)d_out;

    // workspace layout (needs ~23.1 MB; round-2 evidence shows ws >= 40 MB)
    const size_t GBUF_B = (size_t)NB * LEN * 3 * sizeof(float);     // 6,291,456
    const size_t WTF_B  = (size_t)MSZ * COUT * sizeof(short);       // 24,576
    float*          gbuf = (float*)d_ws;
    unsigned short* wtf  = (unsigned short*)((char*)d_ws + GBUF_B);
    unsigned int*   xt32 = (unsigned int*)((char*)d_ws + GBUF_B + WTF_B);
    unsigned short* xt16 = (unsigned short*)xt32;

    fused_off_trans<<<NB * (LEN / 128), 256, 0, stream>>>(x, w_off, b_off, gbuf, xt32);
    wfrag_kernel<<<24, 512, 0, stream>>>(w, wtf);
    dconv3_kernel<<<NB * 128, 256, 0, stream>>>(xt16, wtf, b, gbuf, out);
}

// Round 4
// 56.557 us; speedup vs baseline: 3.6207x; 1.0552x over previous
//
#include <hip/hip_runtime.h>
#include <hip/hip_bf16.h>
#include <math.h>

#define NB   16
#define CIN  64
#define LEN  8192
#define LP2  8195     // rows: 0 = left pad(0), 1..8192 = x, 8193/8194 = right pad(0)
#define COUT 64
#define MSZ  192

typedef float  f32x4  __attribute__((ext_vector_type(4)));
typedef short  bf16x8 __attribute__((ext_vector_type(8)));

static __device__ inline unsigned short f2bf(float f) {
    __hip_bfloat16 h = __float2bfloat16(f);
    return *reinterpret_cast<unsigned short*>(&h);
}

// ---------------- Kernel F: fused offset-conv + transpose-to-bf16 ----------------
__global__ __launch_bounds__(256) void fused_off_trans(
    const float* __restrict__ x, const float* __restrict__ w_off,
    const float* __restrict__ b_off, float* __restrict__ gbuf,
    unsigned int* __restrict__ xt32)
{
    __shared__ float tile[64][131];
    __shared__ float wk[576];
    int tid = threadIdx.x;
    int n = blockIdx.x >> 6;
    int t = blockIdx.x & 63;
    int l0 = t << 7;

    for (int i = tid; i < 576; i += 256) {
        int k = i / 192, rem = i - k * 192;
        wk[i] = w_off[2 * k * 192 + rem];
    }
    for (int j = tid; j < 64 * 130; j += 256) {
        int cc = j / 130, ll = j - cc * 130;
        int gl = l0 - 1 + ll;
        float v = (gl >= 0 && gl < LEN) ? x[((size_t)n * CIN + cc) * LEN + gl] : 0.f;
        tile[cc][ll] = v;
    }
    __syncthreads();

    {
        int l_loc = tid >> 1, h = tid & 1;
        int c0 = h << 5;
        float a0 = 0.f, a1 = 0.f, a2 = 0.f;
        #pragma unroll
        for (int ci = 0; ci < 32; ++ci) {
            int cc = c0 + ci;
            float xm = tile[cc][l_loc];
            float x0 = tile[cc][l_loc + 1];
            float xp = tile[cc][l_loc + 2];
            const float* w0 = &wk[cc * 3];
            const float* w1 = &wk[192 + cc * 3];
            const float* w2 = &wk[384 + cc * 3];
            a0 = fmaf(w0[0], xm, a0); a0 = fmaf(w0[1], x0, a0); a0 = fmaf(w0[2], xp, a0);
            a1 = fmaf(w1[0], xm, a1); a1 = fmaf(w1[1], x0, a1); a1 = fmaf(w1[2], xp, a1);
            a2 = fmaf(w2[0], xm, a2); a2 = fmaf(w2[1], x0, a2); a2 = fmaf(w2[2], xp, a2);
        }
        a0 += __shfl_xor(a0, 1);
        a1 += __shfl_xor(a1, 1);
        a2 += __shfl_xor(a2, 1);
        if (h == 0) {
            int l = l0 + l_loc;
            float base = (float)(l + 1);
            float g0 = fminf(fmaxf(base + a0 + b_off[0], 0.f), 8193.f);
            float g1 = fminf(fmaxf(base + a1 + b_off[2], 0.f), 8193.f);
            float g2 = fminf(fmaxf(base + a2 + b_off[4], 0.f), 8193.f);
            size_t gi = ((size_t)n * LEN + l) * 3;
            gbuf[gi + 0] = g0; gbuf[gi + 1] = g1; gbuf[gi + 2] = g2;
        }
    }

    for (int j = tid; j < 128 * 32; j += 256) {
        int ll = j >> 5, cp = j & 31;
        int c = cp << 1;
        unsigned int u = ((unsigned int)f2bf(tile[c + 1][ll + 1]) << 16) | f2bf(tile[c][ll + 1]);
        xt32[((size_t)n * LP2 + 1 + l0 + ll) * 32 + cp] = u;
    }
    if (t == 0  && tid < 32) xt32[((size_t)n * LP2) * 32 + tid] = 0u;
    if (t == 63 && tid < 64) xt32[((size_t)n * LP2 + 8193 + (tid >> 5)) * 32 + (tid & 31)] = 0u;
}

// ---------------- Kernel W: pack w into MFMA B-fragment order (bf16) ----------------
__global__ __launch_bounds__(512) void wfrag_kernel(
    const float* __restrict__ w, unsigned short* __restrict__ wtf)
{
    int b = blockIdx.x;             // 24 blocks: b = ot*6 + ks
    int ot = b / 6, ks = b - ot * 6;
    int t = threadIdx.x;
    int l = t >> 3, s = t & 7;
    int o = ot * 16 + (l & 15);
    int m = ks * 32 + (l >> 4) * 8 + s;
    wtf[b * 512 + t] = f2bf(w[o * MSZ + m]);
}

// ---------------- Kernel D: pipelined register-gather + bf16 MFMA ----------------
__global__ __launch_bounds__(256) void dconv4_kernel(
    const unsigned short* __restrict__ xt16, const unsigned short* __restrict__ wtf,
    const float* __restrict__ bias, const float* __restrict__ gbuf,
    float* __restrict__ out)
{
    __shared__ __align__(16) int2 meta[MSZ];
    int tid = threadIdx.x;

    // bijective XCD swizzle: XCD x = wg&7 serves only n in {2x, 2x+1}
    // -> per-XCD L2 gather working set = 2 * 1.05 MB < 4 MiB (L2-resident)
    int wg  = blockIdx.x;
    int xcd = wg & 7;
    int tt  = wg >> 3;               // 0..255
    int n   = (xcd << 1) | (tt >> 7);
    int p   = tt & 127;

    if (tid < MSZ) {
        int k = tid >> 6, r = tid & 63;
        int l = (r << 7) | p;
        float g  = gbuf[((size_t)n * LEN + l) * 3 + k];
        float fl = floorf(g);
        meta[tid] = make_int2((int)fl, __float_as_int(g - fl));
    }
    __syncthreads();

    int lane = tid & 63;
    int ct   = tid >> 6;
    int g4   = lane >> 4;
    unsigned int c = (unsigned int)(ct * 16 + (lane & 15));
    const unsigned short* xb = xt16 + (size_t)n * LP2 * 64;

    f32x4 acc[4] = {};

    unsigned int xlA[8], xrA[8], xlB[8], xrB[8];
    float alA[8], alB[8];

    #define ISSUE(KS, XL, XR, AL) do {                                       \
        int mb = (KS) * 32 + g4 * 8;                                         \
        int2 mv[8];                                                          \
        _Pragma("unroll")                                                    \
        for (int q = 0; q < 4; ++q)                                          \
            *(int4*)&mv[q * 2] = *(const int4*)&meta[mb + q * 2];            \
        _Pragma("unroll")                                                    \
        for (int s = 0; s < 8; ++s) {                                        \
            unsigned int off = ((unsigned int)mv[s].x << 6) + c;             \
            (XL)[s] = xb[off];                                               \
            (XR)[s] = xb[off + 64];                                          \
            (AL)[s] = __int_as_float(mv[s].y);                               \
        }                                                                    \
    } while (0)

    #define STEP(KS, XL, XR, AL, NXL, NXR, NAL) do {                         \
        if ((KS) < 5) ISSUE((KS) + 1, NXL, NXR, NAL);                        \
        bf16x8 afrag;                                                        \
        _Pragma("unroll")                                                    \
        for (int s = 0; s < 8; ++s) {                                        \
            float a  = (AL)[s];                                              \
            float vl = __uint_as_float((XL)[s] << 16);                       \
            float vr = __uint_as_float((XR)[s] << 16);                       \
            afrag[s] = (short)f2bf(fmaf(a, vr - vl, vl));                    \
        }                                                                    \
        _Pragma("unroll")                                                    \
        for (int ot = 0; ot < 4; ++ot) {                                     \
            bf16x8 bfrag = *(const bf16x8*)&wtf[(size_t)(((ot * 6 + (KS)) << 6) + lane) << 3]; \
            acc[ot] = __builtin_amdgcn_mfma_f32_16x16x32_bf16(afrag, bfrag, acc[ot], 0, 0, 0); \
        }                                                                    \
    } while (0)

    ISSUE(0, xlA, xrA, alA);
    STEP(0, xlA, xrA, alA, xlB, xrB, alB);
    STEP(1, xlB, xrB, alB, xlA, xrA, alA);
    STEP(2, xlA, xrA, alA, xlB, xrB, alB);
    STEP(3, xlB, xrB, alB, xlA, xrA, alA);
    STEP(4, xlA, xrA, alA, xlB, xrB, alB);
    STEP(5, xlB, xrB, alB, xlA, xrA, alA);

    #undef ISSUE
    #undef STEP

    // D layout: col(o) = lane&15, row(c-block) = (lane>>4)*4 + reg
    int q0 = (p << 6) + ct * 16 + g4 * 4;
    #pragma unroll
    for (int ot = 0; ot < 4; ++ot) {
        int o = ot * 16 + (lane & 15);
        float bb = bias[o];
        float4 r4;
        r4.x = acc[ot][0] + bb;
        r4.y = acc[ot][1] + bb;
        r4.z = acc[ot][2] + bb;
        r4.w = acc[ot][3] + bb;
        *(float4*)&out[((size_t)n * COUT + o) * LEN + q0] = r4;
    }
}

extern "C" void kernel_launch(void* const* d_in, const int* in_sizes, int n_in,
                              void* d_out, int out_size, void* d_ws, size_t ws_size,
                              hipStream_t stream) {
    const float* x     = (const float*)d_in[0];
    const float* w_off = (const float*)d_in[1];
    const float* b_off = (const float*)d_in[2];
    const float* w     = (const float*)d_in[3];
    const float* b     = (const float*)d_in[4];
    float* out = (float*)d_out;

    const size_t GBUF_B = (size_t)NB * LEN * 3 * sizeof(float);     // 6,291,456
    const size_t WTF_B  = (size_t)MSZ * COUT * sizeof(short);       // 24,576
    float*          gbuf = (float*)d_ws;
    unsigned short* wtf  = (unsigned short*)((char*)d_ws + GBUF_B);
    unsigned int*   xt32 = (unsigned int*)((char*)d_ws + GBUF_B + WTF_B);
    unsigned short* xt16 = (unsigned short*)xt32;

    fused_off_trans<<<NB * (LEN / 128), 256, 0, stream>>>(x, w_off, b_off, gbuf, xt32);
    wfrag_kernel<<<24, 512, 0, stream>>>(w, wtf);
    dconv4_kernel<<<NB * 128, 256, 0, stream>>>(xt16, wtf, b, gbuf, out);
}